// Round 7
// baseline (218.457 us; speedup 1.0000x reference)
//
#include <hip/hip_runtime.h>

#define N 4096

typedef float f32x4 __attribute__((ext_vector_type(4)));   // native vec for NT store

// XOR swizzle on float2 slot index: s = e ^ ((e>>4)&15). Bijective per 16-slot
// block. Conflict-free (min-aliasing) for all patterns used:
//   T1w: t*16+i | T1r/T2w: b1*256+j*16+c1 | T2r: j*256+t | T3w: i*256+t | T3r: t*16+k
__device__ __forceinline__ int swz(int e) { return e ^ ((e >> 4) & 15); }

__global__ __launch_bounds__(256, 4) void butterfly6_kernel(
    const float* __restrict__ x,
    const float* __restrict__ w0, const float* __restrict__ w1, const float* __restrict__ w2,
    const float* __restrict__ l0, const float* __restrict__ l1, const float* __restrict__ l2,
    float* __restrict__ out)
{
    __shared__ float2 lds[N];                 // 32768 B
    const int t = threadIdx.x;
    const int b1 = t >> 4, c1 = t & 15;
    const size_t row0 = (size_t)blockIdx.x * 2;
    const float* __restrict__ xA = x + row0 * N;
    const float* __restrict__ xB = xA + N;
    float* __restrict__ oA = out + row0 * N;
    float* __restrict__ oB = oA + N;

    // ---- load 16 contiguous elements per row (4x dwordx4 each) ----
    float vA[16], vB[16];
    {
        const float4* qA = (const float4*)(xA + t * 16);
        const float4* qB = (const float4*)(xB + t * 16);
        #pragma unroll
        for (int q = 0; q < 4; ++q) {
            float4 f = qA[q];
            vA[q*4+0]=f.x; vA[q*4+1]=f.y; vA[q*4+2]=f.z; vA[q*4+3]=f.w;
        }
        #pragma unroll
        for (int q = 0; q < 4; ++q) {
            float4 f = qB[q];
            vB[q*4+0]=f.x; vB[q*4+1]=f.y; vB[q*4+2]=f.z; vB[q*4+3]=f.w;
        }
    }

    // ---- level 2 (thread-local 16x16 matvec, residual = x) ----
    float xwA[16], xwB[16];
    #pragma unroll
    for (int j = 0; j < 16; ++j) {
        float s = w2[j];                 // uniform -> SGPR
        xwA[j] = s * vA[j];
        xwB[j] = s * vB[j];
    }
    #pragma unroll
    for (int i = 0; i < 16; ++i) {
        float a = vA[i], b = vB[i];
        #pragma unroll
        for (int j = 0; j < 16; ++j) {
            float s = l2[i*16 + j];      // uniform -> SGPR
            a = fmaf(s, xwA[j], a);
            b = fmaf(s, xwB[j], b);
        }
        lds[swz(t*16 + i)] = make_float2(a, b);   // wave-private region
    }

    float w1c[16];
    #pragma unroll
    for (int j = 0; j < 16; ++j) w1c[j] = w1[j*16 + c1];

    // ---- level 1 (intra-wave exchange, no barrier, no residual) ----
    float2 y1[16];
    #pragma unroll
    for (int j = 0; j < 16; ++j) {
        float2 p = lds[swz(b1*256 + j*16 + c1)];
        y1[j].x = w1c[j] * p.x;
        y1[j].y = w1c[j] * p.y;
    }
    float2 r1[16];
    #pragma unroll
    for (int i = 0; i < 16; ++i) {
        float a = 0.f, b = 0.f;
        #pragma unroll
        for (int j = 0; j < 16; ++j) {
            float s = l1[i*16 + j];
            a = fmaf(s, y1[j].x, a);
            b = fmaf(s, y1[j].y, b);
        }
        r1[i] = make_float2(a, b);
    }
    #pragma unroll
    for (int i = 0; i < 16; ++i)
        lds[swz(b1*256 + i*16 + c1)] = r1[i];     // WAR on own wave's slots

    float w0c[16];
    #pragma unroll
    for (int j = 0; j < 16; ++j) w0c[j] = w0[j*256 + t];

    __syncthreads();                    // cross-wave handoff into level 0

    // ---- level 0 mix (r-ownership: thread t owns residue r=t), NO residual yet ----
    float2 y0[16];
    #pragma unroll
    for (int j = 0; j < 16; ++j) {
        float2 p = lds[swz(j*256 + t)];
        y0[j].x = w0c[j] * p.x;
        y0[j].y = w0c[j] * p.y;
    }
    float2 r0[16];
    #pragma unroll
    for (int i = 0; i < 16; ++i) {
        float a = 0.f, b = 0.f;
        #pragma unroll
        for (int j = 0; j < 16; ++j) {
            float s = l0[i*16 + j];
            a = fmaf(s, y0[j].x, a);
            b = fmaf(s, y0[j].y, b);
        }
        r0[i] = make_float2(a, b);
    }

    __syncthreads();                    // all y0 reads done -> safe to overwrite
    #pragma unroll
    for (int i = 0; i < 16; ++i)
        lds[swz(i*256 + t)] = r0[i];    // transpose 3: back to flat index i*256+t
    __syncthreads();

    // ---- epilogue in chunk layout: residual from REGISTERS, dwordx4 NT stores ----
    // thread t reads flat e = t*16+k  (matches vA[k] = x[t*16+k])
    float cA[16], cB[16];
    #pragma unroll
    for (int k = 0; k < 16; ++k) {
        float2 p = lds[swz(t*16 + k)];
        cA[k] = p.x + vA[k];
        cB[k] = p.y + vB[k];
    }
    #pragma unroll
    for (int q = 0; q < 4; ++q) {
        f32x4 fa = { cA[q*4+0], cA[q*4+1], cA[q*4+2], cA[q*4+3] };
        f32x4 fb = { cB[q*4+0], cB[q*4+1], cB[q*4+2], cB[q*4+3] };
        __builtin_nontemporal_store(fa, (f32x4*)(oA + t*16 + q*4));
        __builtin_nontemporal_store(fb, (f32x4*)(oB + t*16 + q*4));
    }
}

extern "C" void kernel_launch(void* const* d_in, const int* in_sizes, int n_in,
                              void* d_out, int out_size, void* d_ws, size_t ws_size,
                              hipStream_t stream) {
    const float* x  = (const float*)d_in[0];
    const float* w0 = (const float*)d_in[1];
    const float* w1 = (const float*)d_in[2];
    const float* w2 = (const float*)d_in[3];
    const float* l0 = (const float*)d_in[4];
    const float* l1 = (const float*)d_in[5];
    const float* l2 = (const float*)d_in[6];
    float* out = (float*)d_out;
    const int rows = in_sizes[0] / N;
    butterfly6_kernel<<<rows / 2, 256, 0, stream>>>(x, w0, w1, w2, l0, l1, l2, out);
}

// Round 8
// 75.680 us; speedup vs baseline: 2.8866x; 2.8866x over previous
//
#include <hip/hip_runtime.h>

#define N 4096

// XOR swizzle on float2 slot index: s = e ^ ((e>>4)&15). Bijective per 16-slot
// block. Access patterns (slot -> bank pairs) verified <=4-way aliasing:
//   T1w: t*16+i | T1r/T2w: b1*256+j*16+c1 | T2r: j*256+t | T3w: i*256+t | T3r: t*16+k
__device__ __forceinline__ int swz(int e) { return e ^ ((e >> 4) & 15); }

__global__ __launch_bounds__(256, 4) void butterfly8_kernel(
    const float* __restrict__ x,
    const float* __restrict__ w0, const float* __restrict__ w1, const float* __restrict__ w2,
    const float* __restrict__ l0, const float* __restrict__ l1, const float* __restrict__ l2,
    float* __restrict__ out)
{
    __shared__ float2 lds[N];                 // 32768 B
    const int t = threadIdx.x;
    const int b1 = t >> 4, c1 = t & 15;
    const size_t row0 = (size_t)blockIdx.x * 2;
    const float* __restrict__ xA = x + row0 * N;
    const float* __restrict__ xB = xA + N;
    float* __restrict__ oA = out + row0 * N;
    float* __restrict__ oB = oA + N;

    // ---- load 16 contiguous elements per row (4x dwordx4 each) ----
    float vA[16], vB[16];
    {
        const float4* qA = (const float4*)(xA + t * 16);
        const float4* qB = (const float4*)(xB + t * 16);
        #pragma unroll
        for (int q = 0; q < 4; ++q) {
            float4 f = qA[q];
            vA[q*4+0]=f.x; vA[q*4+1]=f.y; vA[q*4+2]=f.z; vA[q*4+3]=f.w;
        }
        #pragma unroll
        for (int q = 0; q < 4; ++q) {
            float4 f = qB[q];
            vB[q*4+0]=f.x; vB[q*4+1]=f.y; vB[q*4+2]=f.z; vB[q*4+3]=f.w;
        }
    }

    // ---- level 2 (thread-local 16x16 matvec, residual = x) ----
    float xwA[16], xwB[16];
    #pragma unroll
    for (int j = 0; j < 16; ++j) {
        float s = w2[j];                 // uniform -> SGPR
        xwA[j] = s * vA[j];
        xwB[j] = s * vB[j];
    }
    #pragma unroll
    for (int i = 0; i < 16; ++i) {
        float a = vA[i], b = vB[i];
        #pragma unroll
        for (int j = 0; j < 16; ++j) {
            float s = l2[i*16 + j];      // uniform -> SGPR
            a = fmaf(s, xwA[j], a);
            b = fmaf(s, xwB[j], b);
        }
        lds[swz(t*16 + i)] = make_float2(a, b);   // wave-private region
    }

    float w1c[16];
    #pragma unroll
    for (int j = 0; j < 16; ++j) w1c[j] = w1[j*16 + c1];

    // ---- level 1 (intra-wave exchange, no barrier, no residual) ----
    float2 y1[16];
    #pragma unroll
    for (int j = 0; j < 16; ++j) {
        float2 p = lds[swz(b1*256 + j*16 + c1)];
        y1[j].x = w1c[j] * p.x;
        y1[j].y = w1c[j] * p.y;
    }
    float2 r1[16];
    #pragma unroll
    for (int i = 0; i < 16; ++i) {
        float a = 0.f, b = 0.f;
        #pragma unroll
        for (int j = 0; j < 16; ++j) {
            float s = l1[i*16 + j];
            a = fmaf(s, y1[j].x, a);
            b = fmaf(s, y1[j].y, b);
        }
        r1[i] = make_float2(a, b);
    }
    #pragma unroll
    for (int i = 0; i < 16; ++i)
        lds[swz(b1*256 + i*16 + c1)] = r1[i];     // WAR on own wave's slots

    float w0c[16];
    #pragma unroll
    for (int j = 0; j < 16; ++j) w0c[j] = w0[j*256 + t];

    __syncthreads();                    // cross-wave handoff into level 0

    // ---- level 0 mix (thread t owns residue r=t), residual deferred ----
    float2 y0[16];
    #pragma unroll
    for (int j = 0; j < 16; ++j) {
        float2 p = lds[swz(j*256 + t)];
        y0[j].x = w0c[j] * p.x;
        y0[j].y = w0c[j] * p.y;
    }
    float2 r0[16];
    #pragma unroll
    for (int i = 0; i < 16; ++i) {
        float a = 0.f, b = 0.f;
        #pragma unroll
        for (int j = 0; j < 16; ++j) {
            float s = l0[i*16 + j];
            a = fmaf(s, y0[j].x, a);
            b = fmaf(s, y0[j].y, b);
        }
        r0[i] = make_float2(a, b);
    }

    __syncthreads();                    // all y0 reads done -> safe to overwrite
    #pragma unroll
    for (int i = 0; i < 16; ++i)
        lds[swz(i*256 + t)] = r0[i];    // transpose 3: back to flat index i*256+t
    __syncthreads();

    // ---- epilogue in chunk layout: residual from REGISTERS, plain dwordx4 stores
    // (NT removed: these 16B chunks are 64B apart per lane -> need L2 write-combining)
    float cA[16], cB[16];
    #pragma unroll
    for (int k = 0; k < 16; ++k) {
        float2 p = lds[swz(t*16 + k)];
        cA[k] = p.x + vA[k];
        cB[k] = p.y + vB[k];
    }
    #pragma unroll
    for (int q = 0; q < 4; ++q) {
        float4 fa = make_float4(cA[q*4+0], cA[q*4+1], cA[q*4+2], cA[q*4+3]);
        float4 fb = make_float4(cB[q*4+0], cB[q*4+1], cB[q*4+2], cB[q*4+3]);
        *(float4*)(oA + t*16 + q*4) = fa;
        *(float4*)(oB + t*16 + q*4) = fb;
    }
}

extern "C" void kernel_launch(void* const* d_in, const int* in_sizes, int n_in,
                              void* d_out, int out_size, void* d_ws, size_t ws_size,
                              hipStream_t stream) {
    const float* x  = (const float*)d_in[0];
    const float* w0 = (const float*)d_in[1];
    const float* w1 = (const float*)d_in[2];
    const float* w2 = (const float*)d_in[3];
    const float* l0 = (const float*)d_in[4];
    const float* l1 = (const float*)d_in[5];
    const float* l2 = (const float*)d_in[6];
    float* out = (float*)d_out;
    const int rows = in_sizes[0] / N;
    butterfly8_kernel<<<rows / 2, 256, 0, stream>>>(x, w0, w1, w2, l0, l1, l2, out);
}